// Round 3
// baseline (42.369 us; speedup 1.0000x reference)
//
#include <hip/hip_runtime.h>
#include <math.h>

#define D    256
#define DH2  128   // half2 elements per row

typedef _Float16 h2 __attribute__((ext_vector_type(2)));

__device__ __forceinline__ h2 u2h(unsigned u) { return __builtin_bit_cast(h2, u); }

// ---------------- pre-pass: sigmoid -> fp16, row sums (of rounded values) ----
__global__ __launch_bounds__(256)
void prepass(const float* __restrict__ A, const float* __restrict__ B,
             h2* __restrict__ Ah, h2* __restrict__ Bh,
             float* __restrict__ sums /* [2048]: A rows then B rows */) {
    const int wid  = threadIdx.x >> 6;
    const int lane = threadIdx.x & 63;
    const int r    = blockIdx.x * 4 + wid;          // 0..2047
    const bool isA = (r < 1024);
    const int  row = isA ? r : (r - 1024);

    const float* src = (isA ? A : B) + (size_t)row * D;
    float4 g = *(const float4*)(src + 4 * lane);
    float4 s;
    s.x = 1.0f / (1.0f + __expf(-g.x));
    s.y = 1.0f / (1.0f + __expf(-g.y));
    s.z = 1.0f / (1.0f + __expf(-g.z));
    s.w = 1.0f / (1.0f + __expf(-g.w));

    h2 lo, hi;
    lo.x = (_Float16)s.x; lo.y = (_Float16)s.y;
    hi.x = (_Float16)s.z; hi.y = (_Float16)s.w;

    h2* dst = (isA ? Ah : Bh) + (size_t)row * DH2 + 2 * lane;
    dst[0] = lo;
    dst[1] = hi;

    // row sum of the fp16-ROUNDED values (keeps inter/union consistent)
    float rs = ((float)lo.x + (float)lo.y) + ((float)hi.x + (float)hi.y);
    #pragma unroll
    for (int k = 32; k >= 1; k >>= 1)
        rs += __shfl_xor(rs, k, 64);
    if (lane == 0) sums[r] = rs;
}

// ---------------- main: A-row in regs, B via wave-uniform loads, pure VALU ---
__global__ __launch_bounds__(512, 2)
void jaccard_main(const h2* __restrict__ Ah, const h2* __restrict__ Bh,
                  const float* __restrict__ sums, float* __restrict__ out) {
    const int bi   = blockIdx.x;
    const int bj   = blockIdx.y;
    const int lane = threadIdx.x & 63;
    const int w    = __builtin_amdgcn_readfirstlane((int)(threadIdx.x >> 6)); // 0..7

    const int row = bi * 64 + lane;

    // ---- load this lane's full A row into registers (128 half2 = 128 VGPR)
    h2 a[DH2];
    const uint4* ap = (const uint4*)(Ah + (size_t)row * DH2);
    #pragma unroll
    for (int i = 0; i < 32; ++i) {
        uint4 t = ap[i];
        a[4 * i + 0] = u2h(t.x);
        a[4 * i + 1] = u2h(t.y);
        a[4 * i + 2] = u2h(t.z);
        a[4 * i + 3] = u2h(t.w);
    }
    const float sa = sums[row];

    const int colbase = bj * 64 + w * 8;   // this wave's 8 output columns
    float* outT = out + (size_t)1024 * 1024;

    for (int ji = 0; ji < 8; ++ji) {
        const int j = colbase + ji;        // wave-uniform
        const uint4* bp = (const uint4*)(Bh + (size_t)j * DH2);

        h2 p0 = {0, 0}, p1 = {0, 0}, p2 = {0, 0}, p3 = {0, 0};
        #pragma unroll
        for (int c = 0; c < 32; ++c) {
            uint4 bb = bp[c];              // uniform address -> s_load
            h2 m0 = __builtin_elementwise_min(a[4 * c + 0], u2h(bb.x));
            h2 m1 = __builtin_elementwise_min(a[4 * c + 1], u2h(bb.y));
            h2 m2 = __builtin_elementwise_min(a[4 * c + 2], u2h(bb.z));
            h2 m3 = __builtin_elementwise_min(a[4 * c + 3], u2h(bb.w));
            h2 cs = (m0 + m1) + (m2 + m3);
            if ((c & 3) == 0) p0 += cs;
            else if ((c & 3) == 1) p1 += cs;
            else if ((c & 3) == 2) p2 += cs;
            else p3 += cs;
        }
        h2 pt = (p0 + p1) + (p2 + p3);
        const float inter = (float)pt.x + (float)pt.y;

        const float sb  = sums[1024 + j];
        const float val = inter / (sa + sb - inter);

        out [(size_t)row * 1024 + j]   = val;   // sim
        outT[(size_t)j   * 1024 + row] = val;   // sim.T (lanes coalesced)
    }
}

extern "C" void kernel_launch(void* const* d_in, const int* in_sizes, int n_in,
                              void* d_out, int out_size, void* d_ws, size_t ws_size,
                              hipStream_t stream) {
    const float* x1 = (const float*)d_in[0];
    const float* x2 = (const float*)d_in[1];
    float* out = (float*)d_out;

    h2*    Ah   = (h2*)d_ws;                        // 1024*128 h2 = 512 KB
    h2*    Bh   = Ah + (size_t)1024 * DH2;          // 512 KB
    float* sums = (float*)(Bh + (size_t)1024 * DH2); // 2048 floats

    prepass<<<512, 256, 0, stream>>>(x1, x2, Ah, Bh, sums);
    jaccard_main<<<dim3(16, 16), 512, 0, stream>>>(Ah, Bh, sums, out);
}

// Round 4
// 26.001 us; speedup vs baseline: 1.6295x; 1.6295x over previous
//
#include <hip/hip_runtime.h>
#include <math.h>

#define D        256
#define BM       64
#define RSTRIDEH 264                  // halfs per row: 256 + 8 pad -> 528 B (33 x 16B units)
#define RSTRIDEB (RSTRIDEH * 2)       // 528 bytes
#define TILEB    (BM * RSTRIDEB)      // 33792 B per tile

typedef _Float16 h2 __attribute__((ext_vector_type(2)));

__device__ __forceinline__ h2 u2h(unsigned u) { return __builtin_bit_cast(h2, u); }
__device__ __forceinline__ unsigned h2u(h2 h) { return __builtin_bit_cast(unsigned, h); }

__global__ __launch_bounds__(1024, 4)
void jaccard_kernel(const float* __restrict__ A, const float* __restrict__ B,
                    float* __restrict__ out) {
    extern __shared__ char lds[];
    char*  ATile = lds;                       // [64][528 B]
    char*  BTile = lds + TILEB;               // [64][528 B]
    float* sums  = (float*)(lds + 2 * TILEB); // [128]: 0..63 A rows, 64..127 B rows

    const int bi   = blockIdx.x;
    const int bj   = blockIdx.y;
    const int tid  = threadIdx.x;
    const int lane = tid & 63;
    const int wid  = tid >> 6;   // 0..15

    // ---- staging: 128 logical rows over 16 waves; fp32 -> sigmoid -> fp16 ----
    for (int r = wid; r < 2 * BM; r += 16) {
        const bool  isA = (r < BM);
        const int   row = isA ? r : (r - BM);
        const float* src = isA ? (A + (size_t)(bi * BM + row) * D)
                               : (B + (size_t)(bj * BM + row) * D);
        float4 g = *(const float4*)(src + 4 * lane);
        float4 s;
        s.x = 1.0f / (1.0f + __expf(-g.x));
        s.y = 1.0f / (1.0f + __expf(-g.y));
        s.z = 1.0f / (1.0f + __expf(-g.z));
        s.w = 1.0f / (1.0f + __expf(-g.w));

        h2 lo, hi;
        lo.x = (_Float16)s.x; lo.y = (_Float16)s.y;
        hi.x = (_Float16)s.z; hi.y = (_Float16)s.w;

        char* dst = (isA ? ATile : BTile) + (size_t)row * RSTRIDEB + 8 * lane;
        *(uint2*)dst = make_uint2(h2u(lo), h2u(hi));

        // fp32 row sum of the ROUNDED values (keeps union identity consistent)
        float rs = ((float)lo.x + (float)lo.y) + ((float)hi.x + (float)hi.y);
        #pragma unroll
        for (int k = 32; k >= 1; k >>= 1)
            rs += __shfl_xor(rs, k, 64);
        if (lane == 0) sums[r] = rs;
    }
    __syncthreads();

    // ---- main: 2x2 micro-tile, fully unrolled d-loop, immediate-offset reads ----
    const int tx = tid & 31;   // cols {tx, tx+32}
    const int ty = tid >> 5;   // rows {ty, ty+32}

    const char* a0 = ATile + (size_t)ty        * RSTRIDEB;
    const char* a1 = ATile + (size_t)(32 + ty) * RSTRIDEB;
    const char* b0 = BTile + (size_t)tx        * RSTRIDEB;
    const char* b1 = BTile + (size_t)(32 + tx) * RSTRIDEB;

    h2 acc00a = {0,0}, acc00b = {0,0};
    h2 acc01a = {0,0}, acc01b = {0,0};
    h2 acc10a = {0,0}, acc10b = {0,0};
    h2 acc11a = {0,0}, acc11b = {0,0};

    // one chunk = 16 B = 8 halfs; 32 chunks cover D=256
    auto chunk = [&](int c, h2& c00, h2& c01, h2& c10, h2& c11) {
        uint4 va0 = *(const uint4*)(a0 + 16 * c);
        uint4 va1 = *(const uint4*)(a1 + 16 * c);
        uint4 vb0 = *(const uint4*)(b0 + 16 * c);
        uint4 vb1 = *(const uint4*)(b1 + 16 * c);
        h2 A0[4] = { u2h(va0.x), u2h(va0.y), u2h(va0.z), u2h(va0.w) };
        h2 A1[4] = { u2h(va1.x), u2h(va1.y), u2h(va1.z), u2h(va1.w) };
        h2 B0[4] = { u2h(vb0.x), u2h(vb0.y), u2h(vb0.z), u2h(vb0.w) };
        h2 B1[4] = { u2h(vb1.x), u2h(vb1.y), u2h(vb1.z), u2h(vb1.w) };
        #define COMBO(AV, BV, ACC)                                             \
        {                                                                      \
            h2 m0 = __builtin_elementwise_min(AV[0], BV[0]);                   \
            h2 m1 = __builtin_elementwise_min(AV[1], BV[1]);                   \
            h2 m2 = __builtin_elementwise_min(AV[2], BV[2]);                   \
            h2 m3 = __builtin_elementwise_min(AV[3], BV[3]);                   \
            ACC += (m0 + m1) + (m2 + m3);                                      \
        }
        COMBO(A0, B0, c00) COMBO(A0, B1, c01) COMBO(A1, B0, c10) COMBO(A1, B1, c11)
        #undef COMBO
    };

    #pragma unroll
    for (int cc = 0; cc < 16; ++cc) {
        chunk(2 * cc,     acc00a, acc01a, acc10a, acc11a);
        chunk(2 * cc + 1, acc00b, acc01b, acc10b, acc11b);
    }

    // ---- epilogue ----
    const float i00 = ((float)acc00a.x + (float)acc00a.y) + ((float)acc00b.x + (float)acc00b.y);
    const float i01 = ((float)acc01a.x + (float)acc01a.y) + ((float)acc01b.x + (float)acc01b.y);
    const float i10 = ((float)acc10a.x + (float)acc10a.y) + ((float)acc10b.x + (float)acc10b.y);
    const float i11 = ((float)acc11a.x + (float)acc11a.y) + ((float)acc11b.x + (float)acc11b.y);

    const float sa0 = sums[ty],      sa1 = sums[32 + ty];
    const float sb0 = sums[64 + tx], sb1 = sums[96 + tx];

    const float v00 = i00 / (sa0 + sb0 - i00);
    const float v01 = i01 / (sa0 + sb1 - i01);
    const float v10 = i10 / (sa1 + sb0 - i10);
    const float v11 = i11 / (sa1 + sb1 - i11);

    float* outT = out + (size_t)1024 * 1024;
    const int i0 = bi * BM + ty, i1 = i0 + 32;
    const int j0 = bj * BM + tx, j1 = j0 + 32;

    out [(size_t)i0 * 1024 + j0] = v00;
    out [(size_t)i0 * 1024 + j1] = v01;
    out [(size_t)i1 * 1024 + j0] = v10;
    out [(size_t)i1 * 1024 + j1] = v11;
    outT[(size_t)j0 * 1024 + i0] = v00;
    outT[(size_t)j1 * 1024 + i0] = v01;
    outT[(size_t)j0 * 1024 + i1] = v10;
    outT[(size_t)j1 * 1024 + i1] = v11;
}

extern "C" void kernel_launch(void* const* d_in, const int* in_sizes, int n_in,
                              void* d_out, int out_size, void* d_ws, size_t ws_size,
                              hipStream_t stream) {
    const float* x1 = (const float*)d_in[0];
    const float* x2 = (const float*)d_in[1];
    float* out = (float*)d_out;

    const size_t lds_bytes = 2 * TILEB + 128 * sizeof(float);  // ~68.1 KB
    hipFuncSetAttribute((const void*)jaccard_kernel,
                        hipFuncAttributeMaxDynamicSharedMemorySize, (int)lds_bytes);

    dim3 grid(16, 16);   // 256 blocks = 1 per CU, 16 waves/CU
    jaccard_kernel<<<grid, 1024, lds_bytes, stream>>>(x1, x2, out);
}